// Round 6
// baseline (189.028 us; speedup 1.0000x reference)
//
#include <hip/hip_runtime.h>
#include <stdint.h>

// B=8, T=64, N=128, FIN=64, D=64, LAG=8.  Rows (b,t,n): 65536 x 64.
// Single fused kernel, single barrier per lag chunk:
//  - K/V regenerated from X via MFMA into double-buffered LDS (gen of chunk
//    i-1 overlaps compute of chunk i).
//  - P and Q fragments built fully in-register via shfl 4-group exchange
//    (swapped-operand QK^T makes the reduction axis lane-local) — no P LDS.

typedef __bf16 bf16x8 __attribute__((ext_vector_type(8)));
typedef float f32x4 __attribute__((ext_vector_type(4)));

#define MFMA16(a, b, c) __builtin_amdgcn_mfma_f32_16x16x32_bf16((a), (b), (c), 0, 0, 0)

__device__ __forceinline__ unsigned short f2bf(float f) {
    union { float f; unsigned u; } v; v.f = f;
    unsigned r = v.u + 0x7FFFu + ((v.u >> 16) & 1u);
    return (unsigned short)(r >> 16);
}
__device__ __forceinline__ unsigned cvtpk(float lo, float hi) {
    unsigned r;
    asm("v_cvt_pk_bf16_f32 %0, %1, %2" : "=v"(r) : "v"(lo), "v"(hi));
    return r;
}
__device__ __forceinline__ float bflo(unsigned u) {
    union { unsigned x; float f; } v; v.x = u << 16; return v.f;
}
__device__ __forceinline__ float bfhi(unsigned u) {
    union { unsigned x; float f; } v; v.x = u & 0xffff0000u; return v.f;
}
__device__ __forceinline__ f32x4 fzero4() {
    f32x4 z; z[0] = 0.f; z[1] = 0.f; z[2] = 0.f; z[3] = 0.f; return z;
}

// ---------------------------------------------------------------------------
// Kernel 0: one-time weight transpose + bf16 convert.
// Block b: 0->WqT, 1->WkT, 2->WvT (all [64 d][64 f]), 3->WoT [64 dout][128 c].
// ---------------------------------------------------------------------------
__global__ __launch_bounds__(256) void prep_kernel(
    const float* __restrict__ Wq, const float* __restrict__ Wk,
    const float* __restrict__ Wv, const float* __restrict__ Wo,
    unsigned short* __restrict__ WqT, unsigned short* __restrict__ WkT,
    unsigned short* __restrict__ WvT, unsigned short* __restrict__ WoT)
{
    __shared__ float lds[128][65];
    const int b = blockIdx.x, tid = threadIdx.x;
    const float* src = (b == 0) ? Wq : (b == 1) ? Wk : (b == 2) ? Wv : Wo;
    unsigned short* dst = (b == 0) ? WqT : (b == 1) ? WkT : (b == 2) ? WvT : WoT;
    const int n = (b == 3) ? 8192 : 4096;
    for (int i = tid; i < n; i += 256) lds[i >> 6][i & 63] = src[i];
    __syncthreads();
    if (b == 3) {
        for (int i = tid; i < 8192; i += 256) { int d = i >> 7, r = i & 127; dst[i] = f2bf(lds[r][d]); }
    } else {
        for (int i = tid; i < 4096; i += 256) { int d = i >> 6, r = i & 63;  dst[i] = f2bf(lds[r][d]); }
    }
}

// ---------------------------------------------------------------------------
// Fused kernel: one block per (b,t), 8 waves x 16 queries, 512 threads.
// ---------------------------------------------------------------------------
__global__ __launch_bounds__(512, 4) void fused_kernel(
    const float* __restrict__ X,
    const unsigned short* __restrict__ WqT, const unsigned short* __restrict__ WkT,
    const unsigned short* __restrict__ WvT, const unsigned short* __restrict__ WoT,
    const float* __restrict__ bq, const float* __restrict__ bk,
    const float* __restrict__ bv, const float* __restrict__ bo,
    float* __restrict__ Out)
{
    // per buffer: [0,16384) K [128key][64d] swz; [16384,32768) V^T [64d][128key] swz
    __shared__ __align__(16) unsigned char ldsKV[2][32768];
    __shared__ __align__(16) unsigned char ldsW[8192];   // WvT [64 dv][64 f] swz

    const int tid = threadIdx.x;
    const int lane = tid & 63, wvid = tid >> 6;
    const int cl = lane & 15, g = lane >> 4;
    const int bt = ((blockIdx.x & 7) << 6) + (blockIdx.x >> 3);  // XCD swizzle
    const int t = bt & 63;
    const int wq0 = wvid * 16;
    const int q = wq0 + cl;
    const int lo = (t < 7) ? 0 : (t - 7);
    const int swz = (cl & 7) << 4;   // row-XOR for all rows ≡ cl (mod 8)

    // ---- stage WvT -> LDS (8KB; 512 x uint4) ----
    {
        const uint4* wv4 = (const uint4*)WvT;
        const int r = tid >> 3, c0 = (tid & 7) * 8;
        *(uint4*)(ldsW + ((r * 128 + c0 * 2) ^ ((r & 7) << 4))) = wv4[tid];
    }

    // ---- hoisted K-weight A-frags (32 VGPR) ----
    bf16x8 wkF[4][2];
#pragma unroll
    for (int dt = 0; dt < 4; ++dt)
#pragma unroll
        for (int kk = 0; kk < 2; ++kk)
            wkF[dt][kk] = *(const bf16x8*)(WkT + (dt * 16 + cl) * 64 + kk * 32 + g * 8);

    // biases: bk packed bf16 (8 regs), bv scalar per dt
    uint2 bkp[4]; float bvs[4];
#pragma unroll
    for (int dt = 0; dt < 4; ++dt) {
        float4 b4 = *(const float4*)(bk + dt * 16 + g * 4);
        bkp[dt].x = cvtpk(b4.x, b4.y);
        bkp[dt].y = cvtpk(b4.z, b4.w);
        bvs[dt] = bv[dt * 16 + cl];
    }

    // in-register 4-group exchange: from (a=even-tile quad, b=odd-tile quad)
    // produce frag words for g'=2(g&1) (wl) and g'=2(g&1)+1 (wh).
    auto xchg = [&](unsigned a, unsigned b, unsigned& wl, unsigned& wh) {
        const int sl = cl + ((g & 1) << 5);
        unsigned ta = (unsigned)__shfl((int)a, sl, 64);
        unsigned tb = (unsigned)__shfl((int)b, sl, 64);
        unsigned ua = (unsigned)__shfl((int)a, sl + 16, 64);
        unsigned ub = (unsigned)__shfl((int)b, sl + 16, 64);
        wl = (g < 2) ? ta : tb;
        wh = (g < 2) ? ua : ub;
    };

    // ---- X rows for st = t ----
    float4 xr0, xr1, xr2, xr3;
    {
        const float* xp = X + ((size_t)bt * 128 + q) * 64;
        xr0 = *(const float4*)(xp + g * 8);
        xr1 = *(const float4*)(xp + g * 8 + 4);
        xr2 = *(const float4*)(xp + 32 + g * 8);
        xr3 = *(const float4*)(xp + 32 + g * 8 + 4);
    }
    bf16x8 xf[2];
    {
        unsigned u0 = cvtpk(xr0.x, xr0.y), u1 = cvtpk(xr0.z, xr0.w);
        unsigned u2 = cvtpk(xr1.x, xr1.y), u3 = cvtpk(xr1.z, xr1.w);
        unsigned wa[4] = {u0, u1, u2, u3};
        xf[0] = *(bf16x8*)wa;
        u0 = cvtpk(xr2.x, xr2.y); u1 = cvtpk(xr2.z, xr2.w);
        u2 = cvtpk(xr3.x, xr3.y); u3 = cvtpk(xr3.z, xr3.w);
        unsigned wb[4] = {u0, u1, u2, u3};
        xf[1] = *(bf16x8*)wb;
    }

    // ---- Q-gen (global WqT) -> qf fully in-register ----
    bf16x8 qf[2];
    {
        unsigned qu[8];
#pragma unroll
        for (int dt = 0; dt < 4; ++dt) {
            const int rw = (dt * 16 + cl) * 64;
            bf16x8 wqa = *(const bf16x8*)(WqT + rw + g * 8);
            bf16x8 wqb = *(const bf16x8*)(WqT + rw + 32 + g * 8);
            f32x4 qacc = fzero4();
            qacc = MFMA16(wqa, xf[0], qacc);
            qacc = MFMA16(wqb, xf[1], qacc);
            float4 bq4 = *(const float4*)(bq + dt * 16 + g * 4);
            float q0 = fmaxf(qacc[0] + bq4.x, 0.f);
            float q1 = fmaxf(qacc[1] + bq4.y, 0.f);
            float q2 = fmaxf(qacc[2] + bq4.z, 0.f);
            float q3 = fmaxf(qacc[3] + bq4.w, 0.f);
            qu[2 * dt] = cvtpk(q0, q1);
            qu[2 * dt + 1] = cvtpk(q2, q3);
        }
#pragma unroll
        for (int kk = 0; kk < 2; ++kk) {
            unsigned w0, w1, w2, w3;
            xchg(qu[4 * kk], qu[4 * kk + 2], w0, w2);
            xchg(qu[4 * kk + 1], qu[4 * kk + 3], w1, w3);
            unsigned ww[4] = {w0, w1, w2, w3};
            qf[kk] = *(bf16x8*)ww;
        }
    }

    // gen K/V chunk from xf into buffer
    auto genKV = [&](unsigned char* bK, unsigned char* bV, bf16x8 xfa, bf16x8 xfb) {
#pragma unroll
        for (int dt = 0; dt < 4; ++dt) {
            const int wrow = dt * 16 + cl;
            bf16x8 wva = *(const bf16x8*)(ldsW + ((wrow * 128 + g * 16) ^ swz));
            bf16x8 wvb = *(const bf16x8*)(ldsW + ((wrow * 128 + 64 + g * 16) ^ swz));
            f32x4 kacc = fzero4(), vacc = fzero4();
            kacc = MFMA16(wkF[dt][0], xfa, kacc);
            kacc = MFMA16(wkF[dt][1], xfb, kacc);
            vacc = MFMA16(xfa, wva, vacc);
            vacc = MFMA16(xfb, wvb, vacc);
            {   // K: lane col key=q, rows d = dt*16+g*4+r
                float k0 = fmaxf(kacc[0] + bflo(bkp[dt].x), 0.f);
                float k1 = fmaxf(kacc[1] + bfhi(bkp[dt].x), 0.f);
                float k2 = fmaxf(kacc[2] + bflo(bkp[dt].y), 0.f);
                float k3 = fmaxf(kacc[3] + bfhi(bkp[dt].y), 0.f);
                uint2 kp; kp.x = cvtpk(k0, k1); kp.y = cvtpk(k2, k3);
                *(uint2*)(bK + ((q * 128 + (dt * 16 + g * 4) * 2) ^ swz)) = kp;
            }
            {   // V: lane col d=dt*16+cl, rows key = wq0+g*4+r
                const int d = dt * 16 + cl;
                float v0 = fmaxf(vacc[0] + bvs[dt], 0.f);
                float v1 = fmaxf(vacc[1] + bvs[dt], 0.f);
                float v2 = fmaxf(vacc[2] + bvs[dt], 0.f);
                float v3 = fmaxf(vacc[3] + bvs[dt], 0.f);
                uint2 vp; vp.x = cvtpk(v0, v1); vp.y = cvtpk(v2, v3);
                *(uint2*)(bV + ((d * 256 + (wq0 + g * 4) * 2) ^ swz)) = vp;
            }
        }
    };

    __syncthreads();   // ldsW staged

    // prologue: prefetch X(t-1), gen chunk t -> buf0
    if (t > lo) {
        const float* xp = X + (((size_t)bt - 1) * 128 + q) * 64;
        xr0 = *(const float4*)(xp + g * 8);
        xr1 = *(const float4*)(xp + g * 8 + 4);
        xr2 = *(const float4*)(xp + 32 + g * 8);
        xr3 = *(const float4*)(xp + 32 + g * 8 + 4);
    }
    genKV(ldsKV[0], ldsKV[0] + 16384, xf[0], xf[1]);

    f32x4 o[4];
#pragma unroll
    for (int ni = 0; ni < 4; ++ni) o[ni] = fzero4();
    float lsum = 0.f;

    for (int st = t; st >= lo; --st) {
        const int cur = (t - st) & 1;
        unsigned char* bufK = ldsKV[cur];
        unsigned char* bufV = ldsKV[cur] + 16384;

        __syncthreads();   // buf[cur] gen-writes visible; prior reads of buf[cur^1] done

        if (st > lo) {     // gen chunk st-1 into the other buffer (overlaps compute)
            bf16x8 xfa, xfb;
            {
                unsigned u0 = cvtpk(xr0.x, xr0.y), u1 = cvtpk(xr0.z, xr0.w);
                unsigned u2 = cvtpk(xr1.x, xr1.y), u3 = cvtpk(xr1.z, xr1.w);
                unsigned wa[4] = {u0, u1, u2, u3};
                xfa = *(bf16x8*)wa;
                u0 = cvtpk(xr2.x, xr2.y); u1 = cvtpk(xr2.z, xr2.w);
                u2 = cvtpk(xr3.x, xr3.y); u3 = cvtpk(xr3.z, xr3.w);
                unsigned wb[4] = {u0, u1, u2, u3};
                xfb = *(bf16x8*)wb;
            }
            if (st > lo + 1) {   // prefetch X for st-2 (drained only at next barrier)
                const float* xp = X + (((size_t)(bt - (t - st) - 2)) * 128 + q) * 64;
                xr0 = *(const float4*)(xp + g * 8);
                xr1 = *(const float4*)(xp + g * 8 + 4);
                xr2 = *(const float4*)(xp + 32 + g * 8);
                xr3 = *(const float4*)(xp + 32 + g * 8 + 4);
            }
            genKV(ldsKV[cur ^ 1], ldsKV[cur ^ 1] + 16384, xfa, xfb);
        }

        // ---- QK^T (swapped) + exp + in-register P-frag build, 2-key-tile quarters ----
        bf16x8 paf[4];
#pragma unroll
        for (int j = 0; j < 4; ++j) {
            const int keyA = (2 * j) * 16 + cl, keyB = keyA + 16;
            bf16x8 kfa0 = *(const bf16x8*)(bufK + ((keyA * 128 + g * 16) ^ swz));
            bf16x8 kfa1 = *(const bf16x8*)(bufK + ((keyA * 128 + 64 + g * 16) ^ swz));
            bf16x8 kfb0 = *(const bf16x8*)(bufK + ((keyB * 128 + g * 16) ^ swz));
            bf16x8 kfb1 = *(const bf16x8*)(bufK + ((keyB * 128 + 64 + g * 16) ^ swz));
            f32x4 sA = fzero4(), sB = fzero4();
            sA = MFMA16(kfa0, qf[0], sA);
            sA = MFMA16(kfa1, qf[1], sA);
            sB = MFMA16(kfb0, qf[0], sB);
            sB = MFMA16(kfb1, qf[1], sB);
            float pA0 = __expf(sA[0] * 0.125f), pA1 = __expf(sA[1] * 0.125f);
            float pA2 = __expf(sA[2] * 0.125f), pA3 = __expf(sA[3] * 0.125f);
            float pB0 = __expf(sB[0] * 0.125f), pB1 = __expf(sB[1] * 0.125f);
            float pB2 = __expf(sB[2] * 0.125f), pB3 = __expf(sB[3] * 0.125f);
            lsum += ((pA0 + pA1) + (pA2 + pA3)) + ((pB0 + pB1) + (pB2 + pB3));
            unsigned a0 = cvtpk(pA0, pA1), a1 = cvtpk(pA2, pA3);
            unsigned b0 = cvtpk(pB0, pB1), b1 = cvtpk(pB2, pB3);
            unsigned w0, w1, w2, w3;
            xchg(a0, b0, w0, w2);
            xchg(a1, b1, w1, w3);
            unsigned ww[4] = {w0, w1, w2, w3};
            paf[j] = *(bf16x8*)ww;
        }

        // ---- O += P V ----
#pragma unroll
        for (int kk2 = 0; kk2 < 4; ++kk2) {
#pragma unroll
            for (int ni = 0; ni < 4; ++ni) {
                const int d = ni * 16 + cl;
                bf16x8 vf = *(const bf16x8*)(bufV + ((d * 256 + (kk2 * 32 + g * 8) * 2) ^ swz));
                o[ni] = MFMA16(paf[kk2], vf, o[ni]);
            }
        }
    }

    // ---- row sums ----
    float ls = lsum;
    ls += __shfl_xor(ls, 16, 64);
    ls += __shfl_xor(ls, 32, 64);
    if (t < 7) ls += 128.0f * (float)(7 - t);   // padded lags contribute exp(0)=1 each
    float inv[4];
#pragma unroll
    for (int r = 0; r < 4; ++r) inv[r] = 1.0f / __shfl(ls, g * 4 + r, 64);

    __syncthreads();   // all waves done reading K/V buffers

    // agg -> ldsKV[0] K-region as h rows [128 q][64 c] bf16 (swizzled)
    unsigned char* ldsH = ldsKV[0];
    unsigned char* ldsWo = ldsKV[0] + 16384;
#pragma unroll
    for (int ni = 0; ni < 4; ++ni)
#pragma unroll
        for (int r = 0; r < 4; ++r) {
            const int qq = wq0 + g * 4 + r;
            const int d = ni * 16 + cl;
            *(unsigned short*)(ldsH + ((qq * 128 + d * 2) ^ ((qq & 7) << 4))) =
                f2bf(o[ni][r] * inv[r]);
        }

    // stage Wo^T [64 dout][128 c] bf16 (vector copies)
    {
        const uint4* wo4 = (const uint4*)WoT;
#pragma unroll
        for (int j = 0; j < 2; ++j) {
            const int i = tid + j * 512;
            const int d = i >> 4, c0 = (i & 15) * 8;
            *(uint4*)(ldsWo + ((d * 256 + c0 * 2) ^ ((d & 7) << 4))) = wo4[i];
        }
    }
    __syncthreads();

    // out = relu([Q | agg] @ Wo + bo)
    f32x4 h2[4];
#pragma unroll
    for (int ni = 0; ni < 4; ++ni) h2[ni] = fzero4();
#pragma unroll
    for (int kk = 0; kk < 4; ++kk) {
        bf16x8 ha;
        if (kk < 2) {
            ha = qf[kk];
        } else {
            ha = *(const bf16x8*)(ldsH + ((q * 128 + ((kk - 2) * 32 + g * 8) * 2) ^ swz));
        }
#pragma unroll
        for (int ni = 0; ni < 4; ++ni) {
            const int dd = ni * 16 + cl;
            bf16x8 wb = *(const bf16x8*)(ldsWo + ((dd * 256 + (kk * 32 + g * 8) * 2) ^ swz));
            h2[ni] = MFMA16(ha, wb, h2[ni]);
        }
    }
#pragma unroll
    for (int ni = 0; ni < 4; ++ni) {
        const float b = bo[ni * 16 + cl];
#pragma unroll
        for (int r = 0; r < 4; ++r) {
            float v = h2[ni][r] + b;
            v = v > 0.f ? v : 0.f;
            Out[((size_t)bt * 128 + wq0 + g * 4 + r) * 64 + ni * 16 + cl] = v;
        }
    }
}

// ---------------------------------------------------------------------------
extern "C" void kernel_launch(void* const* d_in, const int* in_sizes, int n_in,
                              void* d_out, int out_size, void* d_ws, size_t ws_size,
                              hipStream_t stream) {
    const float* X  = (const float*)d_in[0];
    const float* Wq = (const float*)d_in[1];
    const float* bq = (const float*)d_in[2];
    const float* Wk = (const float*)d_in[3];
    const float* bk = (const float*)d_in[4];
    const float* Wv = (const float*)d_in[5];
    const float* bv = (const float*)d_in[6];
    const float* Wo = (const float*)d_in[7];
    const float* bo = (const float*)d_in[8];
    float* Out = (float*)d_out;

    unsigned short* WqT = (unsigned short*)d_ws;      // 40 KB of weight tables
    unsigned short* WkT = WqT + 4096;
    unsigned short* WvT = WqT + 8192;
    unsigned short* WoT = WqT + 12288;

    hipLaunchKernelGGL(prep_kernel, dim3(4), dim3(256), 0, stream,
                       Wq, Wk, Wv, Wo, WqT, WkT, WvT, WoT);
    hipLaunchKernelGGL(fused_kernel, dim3(512), dim3(512), 0, stream,
                       X, WqT, WkT, WvT, WoT, bq, bk, bv, bo, Out);
}

// Round 8
// 137.453 us; speedup vs baseline: 1.3752x; 1.3752x over previous
//
#include <hip/hip_runtime.h>
#include <stdint.h>

// B=8, T=64, N=128, FIN=64, D=64, LAG=8.  Rows (b,t,n): 65536 x 64.
// Single fused kernel, 2 barriers per lag chunk (proven-safe structure):
//  - K/V regenerated from X via MFMA into a single LDS buffer.
//  - P and Q fragments built fully in-register via shfl 4-group exchange
//    (swapped-operand QK^T makes the reduction axis lane-local) — no P LDS.
// LESSONS ENCODED:
//  * __launch_bounds__(512,2): 2nd arg is min waves per EU; (512,4) caps
//    VGPR at 128 -> catastrophic scratch spill (273MB FETCH, round 6).
//  * 1-barrier double-buffered genKV overlap RACES (round 7 fail: passed
//    only in the spilled build where scratch latency acted as a fence).
//    Keep 2 barriers per chunk.

typedef __bf16 bf16x8 __attribute__((ext_vector_type(8)));
typedef float f32x4 __attribute__((ext_vector_type(4)));

#define MFMA16(a, b, c) __builtin_amdgcn_mfma_f32_16x16x32_bf16((a), (b), (c), 0, 0, 0)

__device__ __forceinline__ unsigned short f2bf(float f) {
    union { float f; unsigned u; } v; v.f = f;
    unsigned r = v.u + 0x7FFFu + ((v.u >> 16) & 1u);
    return (unsigned short)(r >> 16);
}
__device__ __forceinline__ unsigned cvtpk(float lo, float hi) {
    unsigned r;
    asm("v_cvt_pk_bf16_f32 %0, %1, %2" : "=v"(r) : "v"(lo), "v"(hi));
    return r;
}
__device__ __forceinline__ float bflo(unsigned u) {
    union { unsigned x; float f; } v; v.x = u << 16; return v.f;
}
__device__ __forceinline__ float bfhi(unsigned u) {
    union { unsigned x; float f; } v; v.x = u & 0xffff0000u; return v.f;
}
__device__ __forceinline__ f32x4 fzero4() {
    f32x4 z; z[0] = 0.f; z[1] = 0.f; z[2] = 0.f; z[3] = 0.f; return z;
}

// ---------------------------------------------------------------------------
// Kernel 0: one-time weight transpose + bf16 convert.
// Block b: 0->WqT, 1->WkT, 2->WvT (all [64 d][64 f]), 3->WoT [64 dout][128 c].
// ---------------------------------------------------------------------------
__global__ __launch_bounds__(256) void prep_kernel(
    const float* __restrict__ Wq, const float* __restrict__ Wk,
    const float* __restrict__ Wv, const float* __restrict__ Wo,
    unsigned short* __restrict__ WqT, unsigned short* __restrict__ WkT,
    unsigned short* __restrict__ WvT, unsigned short* __restrict__ WoT)
{
    __shared__ float lds[128][65];
    const int b = blockIdx.x, tid = threadIdx.x;
    const float* src = (b == 0) ? Wq : (b == 1) ? Wk : (b == 2) ? Wv : Wo;
    unsigned short* dst = (b == 0) ? WqT : (b == 1) ? WkT : (b == 2) ? WvT : WoT;
    const int n = (b == 3) ? 8192 : 4096;
    for (int i = tid; i < n; i += 256) lds[i >> 6][i & 63] = src[i];
    __syncthreads();
    if (b == 3) {
        for (int i = tid; i < 8192; i += 256) { int d = i >> 7, r = i & 127; dst[i] = f2bf(lds[r][d]); }
    } else {
        for (int i = tid; i < 4096; i += 256) { int d = i >> 6, r = i & 63;  dst[i] = f2bf(lds[r][d]); }
    }
}

// ---------------------------------------------------------------------------
// Fused kernel: one block per (b,t), 8 waves x 16 queries, 512 threads.
// ---------------------------------------------------------------------------
__global__ __launch_bounds__(512, 2) void fused_kernel(
    const float* __restrict__ X,
    const unsigned short* __restrict__ WqT, const unsigned short* __restrict__ WkT,
    const unsigned short* __restrict__ WoT,
    const float* __restrict__ bq, const float* __restrict__ bk,
    const float* __restrict__ bv, const float* __restrict__ bo,
    float* __restrict__ Out)
{
    // [0,16384) K [128key][64d] swz; [16384,32768) V^T [64d][128key] swz
    // epilogue reuse: [0,16384) h rows; [16384,32768) Wo^T
    __shared__ __align__(16) unsigned char ldsKV[32768];
    // W table: rows 0-63 = WkT [dk][f], rows 64-127 = WvT [dv][f], swz
    __shared__ __align__(16) unsigned char ldsW[16384];

    const int tid = threadIdx.x;
    const int lane = tid & 63, wvid = tid >> 6;
    const int cl = lane & 15, g = lane >> 4;
    const int bt = ((blockIdx.x & 7) << 6) + (blockIdx.x >> 3);  // XCD swizzle
    const int t = bt & 63;
    const int wq0 = wvid * 16;
    const int q = wq0 + cl;
    const int lo = (t < 7) ? 0 : (t - 7);
    const int swz = (cl & 7) << 4;   // row-XOR for all rows ≡ cl (mod 8)

    unsigned char* bufK = ldsKV;
    unsigned char* bufV = ldsKV + 16384;

    // ---- stage WkT||WvT -> ldsW (16KB; contiguous in d_ws: WkT then WvT) ----
    {
        const uint4* w4 = (const uint4*)WkT;   // 1024 x uint4 covers Wk + Wv
#pragma unroll
        for (int j = 0; j < 2; ++j) {
            const int i = tid + j * 512;
            const int r = i >> 3, c0 = (i & 7) * 8;
            *(uint4*)(ldsW + ((r * 128 + c0 * 2) ^ ((r & 7) << 4))) = w4[i];
        }
    }

    // biases: bk packed bf16 (8 regs), bv scalar per dt
    uint2 bkp[4]; float bvs[4];
#pragma unroll
    for (int dt = 0; dt < 4; ++dt) {
        float4 b4 = *(const float4*)(bk + dt * 16 + g * 4);
        bkp[dt].x = cvtpk(b4.x, b4.y);
        bkp[dt].y = cvtpk(b4.z, b4.w);
        bvs[dt] = bv[dt * 16 + cl];
    }

    // in-register 4-group exchange: from (a=even-tile quad, b=odd-tile quad)
    // produce frag words for g'=2(g&1) (wl) and g'=2(g&1)+1 (wh).
    auto xchg = [&](unsigned a, unsigned b, unsigned& wl, unsigned& wh) {
        const int sl = cl + ((g & 1) << 5);
        unsigned ta = (unsigned)__shfl((int)a, sl, 64);
        unsigned tb = (unsigned)__shfl((int)b, sl, 64);
        unsigned ua = (unsigned)__shfl((int)a, sl + 16, 64);
        unsigned ub = (unsigned)__shfl((int)b, sl + 16, 64);
        wl = (g < 2) ? ta : tb;
        wh = (g < 2) ? ua : ub;
    };

    // ---- X rows for st = t ----
    float4 xr0, xr1, xr2, xr3;
    {
        const float* xp = X + ((size_t)bt * 128 + q) * 64;
        xr0 = *(const float4*)(xp + g * 8);
        xr1 = *(const float4*)(xp + g * 8 + 4);
        xr2 = *(const float4*)(xp + 32 + g * 8);
        xr3 = *(const float4*)(xp + 32 + g * 8 + 4);
    }

    f32x4 o[4];
#pragma unroll
    for (int ni = 0; ni < 4; ++ni) o[ni] = fzero4();
    float lsum = 0.f;
    bf16x8 qf[2];

    for (int st = t; st >= lo; --st) {
        __syncthreads();   // prev chunk reads done (1st iter: ldsW staged)

        // xf from (pre)fetched registers
        bf16x8 xf[2];
        {
            unsigned u0 = cvtpk(xr0.x, xr0.y), u1 = cvtpk(xr0.z, xr0.w);
            unsigned u2 = cvtpk(xr1.x, xr1.y), u3 = cvtpk(xr1.z, xr1.w);
            unsigned wa[4] = {u0, u1, u2, u3};
            xf[0] = *(bf16x8*)wa;
            u0 = cvtpk(xr2.x, xr2.y); u1 = cvtpk(xr2.z, xr2.w);
            u2 = cvtpk(xr3.x, xr3.y); u3 = cvtpk(xr3.z, xr3.w);
            unsigned wb[4] = {u0, u1, u2, u3};
            xf[1] = *(bf16x8*)wb;
        }
        if (st > lo) {   // prefetch next chunk's X rows (hidden under this chunk)
            const float* xp = X + (((size_t)(bt - (t - st) - 1)) * 128 + q) * 64;
            xr0 = *(const float4*)(xp + g * 8);
            xr1 = *(const float4*)(xp + g * 8 + 4);
            xr2 = *(const float4*)(xp + 32 + g * 8);
            xr3 = *(const float4*)(xp + 32 + g * 8 + 4);
        }

        // ---- gen K chunk D[dk][key] / V chunk D[key][dv] from ldsW weights ----
#pragma unroll
        for (int dt = 0; dt < 4; ++dt) {
            const int rowK = dt * 16 + cl;          // Wk rows 0-63
            const int rowV = 64 + dt * 16 + cl;     // Wv rows 64-127
            bf16x8 wka = *(const bf16x8*)(ldsW + ((rowK * 128 + g * 16) ^ swz));
            bf16x8 wkb = *(const bf16x8*)(ldsW + ((rowK * 128 + 64 + g * 16) ^ swz));
            bf16x8 wva = *(const bf16x8*)(ldsW + ((rowV * 128 + g * 16) ^ swz));
            bf16x8 wvb = *(const bf16x8*)(ldsW + ((rowV * 128 + 64 + g * 16) ^ swz));
            f32x4 kacc = fzero4(), vacc = fzero4();
            kacc = MFMA16(wka, xf[0], kacc);
            kacc = MFMA16(wkb, xf[1], kacc);
            vacc = MFMA16(xf[0], wva, vacc);
            vacc = MFMA16(xf[1], wvb, vacc);
            {   // K: lane col key=q, rows d = dt*16+g*4+r
                float k0 = fmaxf(kacc[0] + bflo(bkp[dt].x), 0.f);
                float k1 = fmaxf(kacc[1] + bfhi(bkp[dt].x), 0.f);
                float k2 = fmaxf(kacc[2] + bflo(bkp[dt].y), 0.f);
                float k3 = fmaxf(kacc[3] + bfhi(bkp[dt].y), 0.f);
                uint2 kp; kp.x = cvtpk(k0, k1); kp.y = cvtpk(k2, k3);
                *(uint2*)(bufK + ((q * 128 + (dt * 16 + g * 4) * 2) ^ swz)) = kp;
            }
            {   // V: lane col d=dt*16+cl, rows key = wq0+g*4+r
                const int d = dt * 16 + cl;
                float v0 = fmaxf(vacc[0] + bvs[dt], 0.f);
                float v1 = fmaxf(vacc[1] + bvs[dt], 0.f);
                float v2 = fmaxf(vacc[2] + bvs[dt], 0.f);
                float v3 = fmaxf(vacc[3] + bvs[dt], 0.f);
                uint2 vp; vp.x = cvtpk(v0, v1); vp.y = cvtpk(v2, v3);
                *(uint2*)(bufV + ((d * 256 + (wq0 + g * 4) * 2) ^ swz)) = vp;
            }
        }

        if (st == t) {   // Q-gen (registers only; global WqT reads)
            unsigned qu[8];
#pragma unroll
            for (int dt = 0; dt < 4; ++dt) {
                const int rw = (dt * 16 + cl) * 64;
                bf16x8 wqa = *(const bf16x8*)(WqT + rw + g * 8);
                bf16x8 wqb = *(const bf16x8*)(WqT + rw + 32 + g * 8);
                f32x4 qacc = fzero4();
                qacc = MFMA16(wqa, xf[0], qacc);
                qacc = MFMA16(wqb, xf[1], qacc);
                float4 bq4 = *(const float4*)(bq + dt * 16 + g * 4);
                float q0 = fmaxf(qacc[0] + bq4.x, 0.f);
                float q1 = fmaxf(qacc[1] + bq4.y, 0.f);
                float q2 = fmaxf(qacc[2] + bq4.z, 0.f);
                float q3 = fmaxf(qacc[3] + bq4.w, 0.f);
                qu[2 * dt] = cvtpk(q0, q1);
                qu[2 * dt + 1] = cvtpk(q2, q3);
            }
#pragma unroll
            for (int kk = 0; kk < 2; ++kk) {
                unsigned w0, w1, w2, w3;
                xchg(qu[4 * kk], qu[4 * kk + 2], w0, w2);
                xchg(qu[4 * kk + 1], qu[4 * kk + 3], w1, w3);
                unsigned ww[4] = {w0, w1, w2, w3};
                qf[kk] = *(bf16x8*)ww;
            }
        }

        __syncthreads();   // K/V visible

        // ---- per 32-key group: QK^T (swapped) + exp + xchg -> pa; then PV ----
#pragma unroll
        for (int j = 0; j < 4; ++j) {
            const int keyA = (2 * j) * 16 + cl, keyB = keyA + 16;
            bf16x8 kfa0 = *(const bf16x8*)(bufK + ((keyA * 128 + g * 16) ^ swz));
            bf16x8 kfa1 = *(const bf16x8*)(bufK + ((keyA * 128 + 64 + g * 16) ^ swz));
            bf16x8 kfb0 = *(const bf16x8*)(bufK + ((keyB * 128 + g * 16) ^ swz));
            bf16x8 kfb1 = *(const bf16x8*)(bufK + ((keyB * 128 + 64 + g * 16) ^ swz));
            f32x4 sA = fzero4(), sB = fzero4();
            sA = MFMA16(kfa0, qf[0], sA);
            sA = MFMA16(kfa1, qf[1], sA);
            sB = MFMA16(kfb0, qf[0], sB);
            sB = MFMA16(kfb1, qf[1], sB);
            float pA0 = __expf(sA[0] * 0.125f), pA1 = __expf(sA[1] * 0.125f);
            float pA2 = __expf(sA[2] * 0.125f), pA3 = __expf(sA[3] * 0.125f);
            float pB0 = __expf(sB[0] * 0.125f), pB1 = __expf(sB[1] * 0.125f);
            float pB2 = __expf(sB[2] * 0.125f), pB3 = __expf(sB[3] * 0.125f);
            lsum += ((pA0 + pA1) + (pA2 + pA3)) + ((pB0 + pB1) + (pB2 + pB3));
            unsigned a0 = cvtpk(pA0, pA1), a1 = cvtpk(pA2, pA3);
            unsigned b0 = cvtpk(pB0, pB1), b1 = cvtpk(pB2, pB3);
            unsigned w0, w1, w2, w3;
            xchg(a0, b0, w0, w2);
            xchg(a1, b1, w1, w3);
            unsigned ww[4] = {w0, w1, w2, w3};
            bf16x8 pa = *(bf16x8*)ww;
#pragma unroll
            for (int ni = 0; ni < 4; ++ni) {
                const int d = ni * 16 + cl;
                bf16x8 vf = *(const bf16x8*)(bufV + ((d * 256 + (j * 32 + g * 8) * 2) ^ swz));
                o[ni] = MFMA16(pa, vf, o[ni]);
            }
        }
    }

    // ---- row sums ----
    float ls = lsum;
    ls += __shfl_xor(ls, 16, 64);
    ls += __shfl_xor(ls, 32, 64);
    if (t < 7) ls += 128.0f * (float)(7 - t);   // padded lags contribute exp(0)=1 each
    float inv[4];
#pragma unroll
    for (int r = 0; r < 4; ++r) inv[r] = 1.0f / __shfl(ls, g * 4 + r, 64);

    __syncthreads();   // all waves done reading K/V

    // agg -> ldsKV K-region as h rows [128 q][64 c] bf16 (swizzled)
    unsigned char* ldsH = ldsKV;
    unsigned char* ldsWo = ldsKV + 16384;
#pragma unroll
    for (int ni = 0; ni < 4; ++ni)
#pragma unroll
        for (int r = 0; r < 4; ++r) {
            const int qq = wq0 + g * 4 + r;
            const int d = ni * 16 + cl;
            *(unsigned short*)(ldsH + ((qq * 128 + d * 2) ^ ((qq & 7) << 4))) =
                f2bf(o[ni][r] * inv[r]);
        }

    // stage Wo^T [64 dout][128 c] bf16 (vector copies)
    {
        const uint4* wo4 = (const uint4*)WoT;
#pragma unroll
        for (int j = 0; j < 2; ++j) {
            const int i = tid + j * 512;
            const int d = i >> 4, c0 = (i & 15) * 8;
            *(uint4*)(ldsWo + ((d * 256 + c0 * 2) ^ ((d & 7) << 4))) = wo4[i];
        }
    }
    __syncthreads();

    // out = relu([Q | agg] @ Wo + bo)
    f32x4 h2[4];
#pragma unroll
    for (int ni = 0; ni < 4; ++ni) h2[ni] = fzero4();
#pragma unroll
    for (int kk = 0; kk < 4; ++kk) {
        bf16x8 ha;
        if (kk < 2) {
            ha = qf[kk];
        } else {
            ha = *(const bf16x8*)(ldsH + ((q * 128 + ((kk - 2) * 32 + g * 8) * 2) ^ swz));
        }
#pragma unroll
        for (int ni = 0; ni < 4; ++ni) {
            const int dd = ni * 16 + cl;
            bf16x8 wb = *(const bf16x8*)(ldsWo + ((dd * 256 + (kk * 32 + g * 8) * 2) ^ swz));
            h2[ni] = MFMA16(ha, wb, h2[ni]);
        }
    }
#pragma unroll
    for (int ni = 0; ni < 4; ++ni) {
        const float b = bo[ni * 16 + cl];
#pragma unroll
        for (int r = 0; r < 4; ++r) {
            float v = h2[ni][r] + b;
            v = v > 0.f ? v : 0.f;
            Out[((size_t)bt * 128 + wq0 + g * 4 + r) * 64 + ni * 16 + cl] = v;
        }
    }
}

// ---------------------------------------------------------------------------
extern "C" void kernel_launch(void* const* d_in, const int* in_sizes, int n_in,
                              void* d_out, int out_size, void* d_ws, size_t ws_size,
                              hipStream_t stream) {
    const float* X  = (const float*)d_in[0];
    const float* Wq = (const float*)d_in[1];
    const float* bq = (const float*)d_in[2];
    const float* Wk = (const float*)d_in[3];
    const float* bk = (const float*)d_in[4];
    const float* Wv = (const float*)d_in[5];
    const float* bv = (const float*)d_in[6];
    const float* Wo = (const float*)d_in[7];
    const float* bo = (const float*)d_in[8];
    float* Out = (float*)d_out;

    unsigned short* WqT = (unsigned short*)d_ws;      // 40 KB of weight tables
    unsigned short* WkT = WqT + 4096;                 // WkT||WvT contiguous (ldsW stage)
    unsigned short* WvT = WqT + 8192;
    unsigned short* WoT = WqT + 12288;

    hipLaunchKernelGGL(prep_kernel, dim3(4), dim3(256), 0, stream,
                       Wq, Wk, Wv, Wo, WqT, WkT, WvT, WoT);
    hipLaunchKernelGGL(fused_kernel, dim3(512), dim3(512), 0, stream,
                       X, WqT, WkT, WoT, bq, bk, bv, bo, Out);
}

// Round 9
// 131.614 us; speedup vs baseline: 1.4362x; 1.0444x over previous
//
#include <hip/hip_runtime.h>
#include <stdint.h>

// B=8, T=64, N=128, FIN=64, D=64, LAG=8.  Rows (b,t,n): 65536 x 64.
// Single fused kernel, 2 barriers per lag chunk.
//  - K/V regenerated from X via MFMA into a single LDS buffer.
//  - ZERO-SHUFFLE P/Q: QK output layout (k=16ki+4g+r) vs PV A-frag layout
//    (k=8g+j) mismatch is resolved by storing V^T key-columns and K d-columns
//    at permuted index phi(32a+16h+4g+r)=32a+8g+4h+r (and permuting WoT's
//    Q-half columns in prep). Contractions are order-invariant, so packed
//    cvtpk pairs feed MFMA directly — no ds_bpermute anywhere in the loop.
// LESSONS ENCODED:
//  * __launch_bounds__(512,2): (512,4) caps VGPR at 128 -> 273MB spill (r6).
//  * 1-barrier double-buffered genKV overlap races (r7). Keep 2 barriers.

typedef __bf16 bf16x8 __attribute__((ext_vector_type(8)));
typedef float f32x4 __attribute__((ext_vector_type(4)));

#define MFMA16(a, b, c) __builtin_amdgcn_mfma_f32_16x16x32_bf16((a), (b), (c), 0, 0, 0)

__device__ __forceinline__ unsigned short f2bf(float f) {
    union { float f; unsigned u; } v; v.f = f;
    unsigned r = v.u + 0x7FFFu + ((v.u >> 16) & 1u);
    return (unsigned short)(r >> 16);
}
__device__ __forceinline__ unsigned cvtpk(float lo, float hi) {
    unsigned r;
    asm("v_cvt_pk_bf16_f32 %0, %1, %2" : "=v"(r) : "v"(lo), "v"(hi));
    return r;
}
__device__ __forceinline__ float bflo(unsigned u) {
    union { unsigned x; float f; } v; v.x = u << 16; return v.f;
}
__device__ __forceinline__ float bfhi(unsigned u) {
    union { unsigned x; float f; } v; v.x = u & 0xffff0000u; return v.f;
}
__device__ __forceinline__ f32x4 fzero4() {
    f32x4 z; z[0] = 0.f; z[1] = 0.f; z[2] = 0.f; z[3] = 0.f; return z;
}

// ---------------------------------------------------------------------------
// Kernel 0: one-time weight transpose + bf16 convert.
// Block b: 0->WqT, 1->WkT, 2->WvT (all [64 d][64 f]); 3->WoT [64 dout][128 c]
// with Q-half (c<64) columns stored at phi(c) for the zero-shuffle out-proj.
// ---------------------------------------------------------------------------
__global__ __launch_bounds__(256) void prep_kernel(
    const float* __restrict__ Wq, const float* __restrict__ Wk,
    const float* __restrict__ Wv, const float* __restrict__ Wo,
    unsigned short* __restrict__ WqT, unsigned short* __restrict__ WkT,
    unsigned short* __restrict__ WvT, unsigned short* __restrict__ WoT)
{
    __shared__ float lds[128][65];
    const int b = blockIdx.x, tid = threadIdx.x;
    const float* src = (b == 0) ? Wq : (b == 1) ? Wk : (b == 2) ? Wv : Wo;
    unsigned short* dst = (b == 0) ? WqT : (b == 1) ? WkT : (b == 2) ? WvT : WoT;
    const int n = (b == 3) ? 8192 : 4096;
    for (int i = tid; i < n; i += 256) lds[i >> 6][i & 63] = src[i];
    __syncthreads();
    if (b == 3) {
        for (int i = tid; i < 8192; i += 256) {
            int d = i >> 7, c = i & 127;
            // phi on the Q-half: 32a+16h+4g+r -> 32a+8g+4h+r
            int cs = (c < 64)
                ? ((c & 32) | (((c >> 2) & 3) << 3) | (((c >> 4) & 1) << 2) | (c & 3))
                : c;
            dst[d * 128 + cs] = f2bf(lds[c][d]);
        }
    } else {
        for (int i = tid; i < 4096; i += 256) { int d = i >> 6, r = i & 63;  dst[i] = f2bf(lds[r][d]); }
    }
}

// ---------------------------------------------------------------------------
// Fused kernel: one block per (b,t), 8 waves x 16 queries, 512 threads.
// ---------------------------------------------------------------------------
__global__ __launch_bounds__(512, 2) void fused_kernel(
    const float* __restrict__ X,
    const unsigned short* __restrict__ WqT, const unsigned short* __restrict__ WkT,
    const unsigned short* __restrict__ WvT, const unsigned short* __restrict__ WoT,
    const float* __restrict__ bq, const float* __restrict__ bk,
    const float* __restrict__ bv, const float* __restrict__ bo,
    float* __restrict__ Out)
{
    // [0,16384) K [128key][64 d-slot] swz; [16384,32768) V^T [64d][128 key-slot] swz
    // epilogue reuse: [0,16384) h rows; [16384,32768) Wo^T
    __shared__ __align__(16) unsigned char ldsKV[32768];
    __shared__ __align__(16) unsigned char ldsW[8192];   // WvT [64 dv][64 f] swz

    const int tid = threadIdx.x;
    const int lane = tid & 63, wvid = tid >> 6;
    const int cl = lane & 15, g = lane >> 4;
    const int bt = ((blockIdx.x & 7) << 6) + (blockIdx.x >> 3);  // XCD swizzle
    const int t = bt & 63;
    const int wq0 = wvid * 16;
    const int q = wq0 + cl;
    const int lo = (t < 7) ? 0 : (t - 7);
    const int swz = (cl & 7) << 4;   // row-XOR for all rows ≡ cl (mod 8)

    unsigned char* bufK = ldsKV;
    unsigned char* bufV = ldsKV + 16384;

    // ---- stage WvT -> ldsW (8KB; one uint4 per thread) ----
    {
        const uint4* wv4 = (const uint4*)WvT;
        const int r = tid >> 3, c0 = (tid & 7) * 8;
        *(uint4*)(ldsW + ((r * 128 + c0 * 2) ^ ((r & 7) << 4))) = wv4[tid];
    }

    // ---- hoisted Wk A-frags (32 VGPR; L2-hot global reads) ----
    bf16x8 wkF[4][2];
#pragma unroll
    for (int dt = 0; dt < 4; ++dt)
#pragma unroll
        for (int kk = 0; kk < 2; ++kk)
            wkF[dt][kk] = *(const bf16x8*)(WkT + (dt * 16 + cl) * 64 + kk * 32 + g * 8);

    // biases: bk packed bf16 (8 regs), bv scalar per dt
    uint2 bkp[4]; float bvs[4];
#pragma unroll
    for (int dt = 0; dt < 4; ++dt) {
        float4 b4 = *(const float4*)(bk + dt * 16 + g * 4);
        bkp[dt].x = cvtpk(b4.x, b4.y);
        bkp[dt].y = cvtpk(b4.z, b4.w);
        bvs[dt] = bv[dt * 16 + cl];
    }

    // ---- X rows for st = t ----
    float4 xr0, xr1, xr2, xr3;
    {
        const float* xp = X + ((size_t)bt * 128 + q) * 64;
        xr0 = *(const float4*)(xp + g * 8);
        xr1 = *(const float4*)(xp + g * 8 + 4);
        xr2 = *(const float4*)(xp + 32 + g * 8);
        xr3 = *(const float4*)(xp + 32 + g * 8 + 4);
    }

    f32x4 o[4];
#pragma unroll
    for (int ni = 0; ni < 4; ++ni) o[ni] = fzero4();
    float lsum = 0.f;
    bf16x8 qf[2];

    for (int st = t; st >= lo; --st) {
        __syncthreads();   // prev chunk reads done (1st iter: ldsW staged)

        // xf from (pre)fetched registers
        bf16x8 xf[2];
        {
            unsigned u0 = cvtpk(xr0.x, xr0.y), u1 = cvtpk(xr0.z, xr0.w);
            unsigned u2 = cvtpk(xr1.x, xr1.y), u3 = cvtpk(xr1.z, xr1.w);
            unsigned wa[4] = {u0, u1, u2, u3};
            xf[0] = *(bf16x8*)wa;
            u0 = cvtpk(xr2.x, xr2.y); u1 = cvtpk(xr2.z, xr2.w);
            u2 = cvtpk(xr3.x, xr3.y); u3 = cvtpk(xr3.z, xr3.w);
            unsigned wb[4] = {u0, u1, u2, u3};
            xf[1] = *(bf16x8*)wb;
        }
        if (st > lo) {   // prefetch next chunk's X rows (hidden under this chunk)
            const float* xp = X + (((size_t)(bt - (t - st) - 1)) * 128 + q) * 64;
            xr0 = *(const float4*)(xp + g * 8);
            xr1 = *(const float4*)(xp + g * 8 + 4);
            xr2 = *(const float4*)(xp + 32 + g * 8);
            xr3 = *(const float4*)(xp + 32 + g * 8 + 4);
        }

        // ---- gen K chunk (d-cols permuted by phi) / V chunk (key-cols permuted) ----
#pragma unroll
        for (int dt = 0; dt < 4; ++dt) {
            const int rowV = dt * 16 + cl;     // Wv rows (actual d)
            bf16x8 wva = *(const bf16x8*)(ldsW + ((rowV * 128 + g * 16) ^ swz));
            bf16x8 wvb = *(const bf16x8*)(ldsW + ((rowV * 128 + 64 + g * 16) ^ swz));
            f32x4 kacc = fzero4(), vacc = fzero4();
            kacc = MFMA16(wkF[dt][0], xf[0], kacc);
            kacc = MFMA16(wkF[dt][1], xf[1], kacc);
            vacc = MFMA16(xf[0], wva, vacc);
            vacc = MFMA16(xf[1], wvb, vacc);
            {   // K: lane row key=q; actual d = dt*16+g*4+r -> slot 32(dt>>1)+8g+4(dt&1)+r
                const int colK = 32 * (dt >> 1) + 8 * g + 4 * (dt & 1);
                float k0 = fmaxf(kacc[0] + bflo(bkp[dt].x), 0.f);
                float k1 = fmaxf(kacc[1] + bfhi(bkp[dt].x), 0.f);
                float k2 = fmaxf(kacc[2] + bflo(bkp[dt].y), 0.f);
                float k3 = fmaxf(kacc[3] + bfhi(bkp[dt].y), 0.f);
                uint2 kp; kp.x = cvtpk(k0, k1); kp.y = cvtpk(k2, k3);
                *(uint2*)(bufK + ((q * 128 + colK * 2) ^ swz)) = kp;
            }
            {   // V: lane row d=dt*16+cl; key 16wvid+4g+r -> slot 32(wvid>>1)+8g+4(wvid&1)+r
                const int d = dt * 16 + cl;
                const int colV = 32 * (wvid >> 1) + 8 * g + 4 * (wvid & 1);
                float v0 = fmaxf(vacc[0] + bvs[dt], 0.f);
                float v1 = fmaxf(vacc[1] + bvs[dt], 0.f);
                float v2 = fmaxf(vacc[2] + bvs[dt], 0.f);
                float v3 = fmaxf(vacc[3] + bvs[dt], 0.f);
                uint2 vp; vp.x = cvtpk(v0, v1); vp.y = cvtpk(v2, v3);
                *(uint2*)(bufV + ((d * 256 + colV * 2) ^ swz)) = vp;
            }
        }

        if (st == t) {   // Q-gen: natural cvtpk pack IS the B-frag (phi on K side)
            unsigned qu[8];
#pragma unroll
            for (int dt = 0; dt < 4; ++dt) {
                const int rw = (dt * 16 + cl) * 64;
                bf16x8 wqa = *(const bf16x8*)(WqT + rw + g * 8);
                bf16x8 wqb = *(const bf16x8*)(WqT + rw + 32 + g * 8);
                f32x4 qacc = fzero4();
                qacc = MFMA16(wqa, xf[0], qacc);
                qacc = MFMA16(wqb, xf[1], qacc);
                float4 bq4 = *(const float4*)(bq + dt * 16 + g * 4);
                float q0 = fmaxf(qacc[0] + bq4.x, 0.f);
                float q1 = fmaxf(qacc[1] + bq4.y, 0.f);
                float q2 = fmaxf(qacc[2] + bq4.z, 0.f);
                float q3 = fmaxf(qacc[3] + bq4.w, 0.f);
                qu[2 * dt] = cvtpk(q0, q1);
                qu[2 * dt + 1] = cvtpk(q2, q3);
            }
#pragma unroll
            for (int kk = 0; kk < 2; ++kk) {
                unsigned ww[4] = {qu[4 * kk], qu[4 * kk + 1], qu[4 * kk + 2], qu[4 * kk + 3]};
                qf[kk] = *(bf16x8*)ww;
            }
        }

        __syncthreads();   // K/V visible

        // ---- per 32-key tile: QK^T (swapped) + exp + direct pack -> PV ----
#pragma unroll
        for (int j = 0; j < 4; ++j) {
            const int keyA = (2 * j) * 16 + cl, keyB = keyA + 16;
            bf16x8 kfa0 = *(const bf16x8*)(bufK + ((keyA * 128 + g * 16) ^ swz));
            bf16x8 kfa1 = *(const bf16x8*)(bufK + ((keyA * 128 + 64 + g * 16) ^ swz));
            bf16x8 kfb0 = *(const bf16x8*)(bufK + ((keyB * 128 + g * 16) ^ swz));
            bf16x8 kfb1 = *(const bf16x8*)(bufK + ((keyB * 128 + 64 + g * 16) ^ swz));
            f32x4 sA = fzero4(), sB = fzero4();
            sA = MFMA16(kfa0, qf[0], sA);
            sA = MFMA16(kfa1, qf[1], sA);
            sB = MFMA16(kfb0, qf[0], sB);
            sB = MFMA16(kfb1, qf[1], sB);
            float pA0 = __expf(sA[0] * 0.125f), pA1 = __expf(sA[1] * 0.125f);
            float pA2 = __expf(sA[2] * 0.125f), pA3 = __expf(sA[3] * 0.125f);
            float pB0 = __expf(sB[0] * 0.125f), pB1 = __expf(sB[1] * 0.125f);
            float pB2 = __expf(sB[2] * 0.125f), pB3 = __expf(sB[3] * 0.125f);
            lsum += ((pA0 + pA1) + (pA2 + pA3)) + ((pB0 + pB1) + (pB2 + pB3));
            // direct A-frag pack (V key-cols pre-permuted by phi -> no shuffle)
            unsigned ww[4];
            ww[0] = cvtpk(pA0, pA1); ww[1] = cvtpk(pA2, pA3);
            ww[2] = cvtpk(pB0, pB1); ww[3] = cvtpk(pB2, pB3);
            bf16x8 pa = *(bf16x8*)ww;
#pragma unroll
            for (int ni = 0; ni < 4; ++ni) {
                const int d = ni * 16 + cl;
                bf16x8 vf = *(const bf16x8*)(bufV + ((d * 256 + (j * 32 + g * 8) * 2) ^ swz));
                o[ni] = MFMA16(pa, vf, o[ni]);
            }
        }
    }

    // ---- row sums ----
    float ls = lsum;
    ls += __shfl_xor(ls, 16, 64);
    ls += __shfl_xor(ls, 32, 64);
    if (t < 7) ls += 128.0f * (float)(7 - t);   // padded lags contribute exp(0)=1 each
    float inv[4];
#pragma unroll
    for (int r = 0; r < 4; ++r) inv[r] = 1.0f / __shfl(ls, g * 4 + r, 64);

    __syncthreads();   // all waves done reading K/V

    // agg -> ldsKV K-region as h rows [128 q][64 c] bf16 (natural d order)
    unsigned char* ldsH = ldsKV;
    unsigned char* ldsWo = ldsKV + 16384;
#pragma unroll
    for (int ni = 0; ni < 4; ++ni)
#pragma unroll
        for (int r = 0; r < 4; ++r) {
            const int qq = wq0 + g * 4 + r;
            const int d = ni * 16 + cl;
            *(unsigned short*)(ldsH + ((qq * 128 + d * 2) ^ ((qq & 7) << 4))) =
                f2bf(o[ni][r] * inv[r]);
        }

    // stage Wo^T [64 dout][128 c-storage] bf16 (Q-half pre-permuted in prep)
    {
        const uint4* wo4 = (const uint4*)WoT;
#pragma unroll
        for (int j = 0; j < 2; ++j) {
            const int i = tid + j * 512;
            const int d = i >> 4, c0 = (i & 15) * 8;
            *(uint4*)(ldsWo + ((d * 256 + c0 * 2) ^ ((d & 7) << 4))) = wo4[i];
        }
    }
    __syncthreads();

    // out = relu([Q | agg] @ Wo + bo)
    f32x4 h2[4];
#pragma unroll
    for (int ni = 0; ni < 4; ++ni) h2[ni] = fzero4();
#pragma unroll
    for (int kk = 0; kk < 4; ++kk) {
        bf16x8 ha;
        if (kk < 2) {
            ha = qf[kk];
        } else {
            ha = *(const bf16x8*)(ldsH + ((q * 128 + ((kk - 2) * 32 + g * 8) * 2) ^ swz));
        }
#pragma unroll
        for (int ni = 0; ni < 4; ++ni) {
            const int dd = ni * 16 + cl;
            bf16x8 wb = *(const bf16x8*)(ldsWo + ((dd * 256 + (kk * 32 + g * 8) * 2) ^ swz));
            h2[ni] = MFMA16(ha, wb, h2[ni]);
        }
    }
#pragma unroll
    for (int ni = 0; ni < 4; ++ni) {
        const float b = bo[ni * 16 + cl];
#pragma unroll
        for (int r = 0; r < 4; ++r) {
            float v = h2[ni][r] + b;
            v = v > 0.f ? v : 0.f;
            Out[((size_t)bt * 128 + wq0 + g * 4 + r) * 64 + ni * 16 + cl] = v;
        }
    }
}

// ---------------------------------------------------------------------------
extern "C" void kernel_launch(void* const* d_in, const int* in_sizes, int n_in,
                              void* d_out, int out_size, void* d_ws, size_t ws_size,
                              hipStream_t stream) {
    const float* X  = (const float*)d_in[0];
    const float* Wq = (const float*)d_in[1];
    const float* bq = (const float*)d_in[2];
    const float* Wk = (const float*)d_in[3];
    const float* bk = (const float*)d_in[4];
    const float* Wv = (const float*)d_in[5];
    const float* bv = (const float*)d_in[6];
    const float* Wo = (const float*)d_in[7];
    const float* bo = (const float*)d_in[8];
    float* Out = (float*)d_out;

    unsigned short* WqT = (unsigned short*)d_ws;      // 40 KB of weight tables
    unsigned short* WkT = WqT + 4096;
    unsigned short* WvT = WqT + 8192;
    unsigned short* WoT = WqT + 12288;

    hipLaunchKernelGGL(prep_kernel, dim3(4), dim3(256), 0, stream,
                       Wq, Wk, Wv, Wo, WqT, WkT, WvT, WoT);
    hipLaunchKernelGGL(fused_kernel, dim3(512), dim3(512), 0, stream,
                       X, WqT, WkT, WvT, WoT, bq, bk, bv, bo, Out);
}